// Round 1
// baseline (202.220 us; speedup 1.0000x reference)
//
#include <hip/hip_runtime.h>
#include <hip/hip_bf16.h>
#include <math.h>

#define N 512
#define DIM 64
#define LXY 24
#define LZ 16

// workspace layout (units: floats from base)
#define WS_Q 0
#define WS_K (N*DIM)
#define WS_V (2*N*DIM)
#define WS_A (3*N*DIM)
#define WS_B (4*N*DIM)
#define WS_ATT (5*N*DIM)
#define WS_MEAN (6*N*DIM)
#define WS_MAX (6*N*DIM + DIM)
#define WS_IDX (6*N*DIM + 2*DIM)   // int region starts here (4-byte units)

// ---------------------------------------------------------------- idx quant
__global__ void k_idx(const float* __restrict__ dist, int* __restrict__ idxp) {
    int p = blockIdx.x * blockDim.x + threadIdx.x;
    if (p >= N * N) return;
    float dx = dist[p * 3 + 0];
    float dy = dist[p * 3 + 1];
    float dz = dist[p * 3 + 2];
    // (d+SIZE)//QUANT with QUANT=0.25 == floor((d+SIZE)*4), exact in f32
    int ix = min((int)floorf((dx + 3.0f) * 4.0f), 23);
    int iy = min((int)floorf((dy + 3.0f) * 4.0f), 23);
    int iz = min((int)floorf((dz + 2.0f) * 4.0f), 15);
    idxp[p] = ix | (iy << 5) | (iz << 10);
}

// ------------------------------------------------- qkv + A/B precompute
// A_i = q_i @ Wg1 + bg1 ; B_j = k_j @ Wg1   (so hidden = relu(A_i - B_j))
__global__ void k_qkv(const float* __restrict__ feat, const float* __restrict__ Wqkv,
                      const float* __restrict__ bqkv, const float* __restrict__ Wg1,
                      const float* __restrict__ bg1, float* __restrict__ ws) {
    __shared__ float frow[DIM];
    __shared__ float qrow[DIM];
    __shared__ float krow[DIM];
    int i = blockIdx.x;
    int c = threadIdx.x;              // 0..191
    if (c < DIM) frow[c] = feat[i * DIM + c];
    __syncthreads();
    float acc = bqkv[c];
#pragma unroll
    for (int kk = 0; kk < DIM; ++kk) acc += frow[kk] * Wqkv[kk * 3 * DIM + c];
    if (c < DIM) {
        ws[WS_Q + i * DIM + c] = acc;
        qrow[c] = acc;
    } else if (c < 2 * DIM) {
        ws[WS_K + i * DIM + (c - DIM)] = acc;
        krow[c - DIM] = acc;
    } else {
        ws[WS_V + i * DIM + (c - 2 * DIM)] = acc;
    }
    __syncthreads();
    if (c < DIM) {
        float a = bg1[c];
#pragma unroll
        for (int kk = 0; kk < DIM; ++kk) a += qrow[kk] * Wg1[kk * DIM + c];
        ws[WS_A + i * DIM + c] = a;
    } else if (c < 2 * DIM) {
        int cc = c - DIM;
        float b = 0.0f;
#pragma unroll
        for (int kk = 0; kk < DIM; ++kk) b += krow[kk] * Wg1[kk * DIM + cc];
        ws[WS_B + i * DIM + cc] = b;
    }
}

// ---------------------------------------------------------- fused attention
// one block per query row i; 4 waves; wave js handles j == js (mod 4)
__global__ __launch_bounds__(256, 2) void k_attn(
    const float* __restrict__ tx, const float* __restrict__ ty,
    const float* __restrict__ tz, const float* __restrict__ Wg2,
    const float* __restrict__ bg2, float* __restrict__ ws,
    const int* __restrict__ idxp) {
    __shared__ float txs[3 * LXY * DIM];
    __shared__ float tys[3 * LXY * DIM];
    __shared__ float tzs[3 * LZ * DIM];
    __shared__ __align__(16) float hid[4][DIM];
    __shared__ float redm[4][DIM];
    __shared__ float redl[4][DIM];
    __shared__ float reda[4][DIM];

    int i = blockIdx.x;
    int tid = threadIdx.x;
    int d = tid & 63;
    int js = tid >> 6;

    for (int t = tid; t < 3 * LXY * DIM; t += 256) {
        txs[t] = tx[t];
        tys[t] = ty[t];
    }
    for (int t = tid; t < 3 * LZ * DIM; t += 256) tzs[t] = tz[t];

    // Wg2 column d cached in registers: wg2c[dp] = Wg2[dp][d]
    float wg2c[DIM];
#pragma unroll
    for (int dp = 0; dp < DIM; ++dp) wg2c[dp] = Wg2[dp * DIM + d];

    float Ar = ws[WS_A + i * DIM + d];
    float qr = ws[WS_Q + i * DIM + d];
    float bg2r = bg2[d];
    const float* Bp = ws + WS_B;
    const float* kp = ws + WS_K;
    const float* vp = ws + WS_V;
    const int* irow = idxp + i * N;

    float m = -INFINITY, l = 0.0f, acc = 0.0f;
    __syncthreads();

    for (int jc = 0; jc < N / 4; ++jc) {
        int j = jc * 4 + js;
        float hv = fmaxf(Ar - Bp[j * DIM + d], 0.0f);
        hid[js][d] = hv;
        float kv = kp[j * DIM + d];
        float vv = vp[j * DIM + d];
        int pk = irow[j];
        __syncthreads();
        // rel[d] = bg2[d] + sum_dp hid[js][dp] * Wg2[dp][d]
        float r = bg2r;
        const float4* hv4 = (const float4*)(&hid[js][0]);
#pragma unroll
        for (int t4 = 0; t4 < DIM / 4; ++t4) {
            float4 h4 = hv4[t4];
            r += h4.x * wg2c[t4 * 4 + 0];
            r += h4.y * wg2c[t4 * 4 + 1];
            r += h4.z * wg2c[t4 * 4 + 2];
            r += h4.w * wg2c[t4 * 4 + 3];
        }
        int ix = pk & 31, iy = (pk >> 5) & 31, iz = pk >> 10;
        float eq = txs[0 * LXY * DIM + ix * DIM + d] + tys[0 * LXY * DIM + iy * DIM + d] +
                   tzs[0 * LZ * DIM + iz * DIM + d];
        float ek = txs[1 * LXY * DIM + ix * DIM + d] + tys[1 * LXY * DIM + iy * DIM + d] +
                   tzs[1 * LZ * DIM + iz * DIM + d];
        float ev = txs[2 * LXY * DIM + ix * DIM + d] + tys[2 * LXY * DIM + iy * DIM + d] +
                   tzs[2 * LZ * DIM + iz * DIM + d];
        float rel = r + qr * eq + kv * ek;
        float vvv = vv + ev;
        // online softmax (per channel d, over this wave's j subset)
        float mn = fmaxf(m, rel);
        float sc = __expf(m - mn);
        float p = __expf(rel - mn);
        l = l * sc + p;
        acc = acc * sc + p * vvv;
        m = mn;
        __syncthreads();
    }

    redm[js][d] = m;
    redl[js][d] = l;
    reda[js][d] = acc;
    __syncthreads();
    if (js == 0) {
        float M = redm[0][d];
#pragma unroll
        for (int s = 1; s < 4; ++s) M = fmaxf(M, redm[s][d]);
        float L = 0.0f, A2 = 0.0f;
#pragma unroll
        for (int s = 0; s < 4; ++s) {
            float e = __expf(redm[s][d] - M);
            L += redl[s][d] * e;
            A2 += reda[s][d] * e;
        }
        ws[WS_ATT + i * DIM + d] = A2 / L;
    }
}

// ------------------------------------------------------- column mean / max
__global__ void k_colred(const float* __restrict__ att, float* __restrict__ meanv,
                         float* __restrict__ maxv) {
    __shared__ float ssum[16][DIM];
    __shared__ float smax[16][DIM];
    int tid = threadIdx.x;            // 0..1023
    int c = tid & 63, g = tid >> 6;
    float s = 0.0f, mx = -INFINITY;
    for (int r = g; r < N; r += 16) {
        float v = att[r * DIM + c];
        s += v;
        mx = fmaxf(mx, v);
    }
    ssum[g][c] = s;
    smax[g][c] = mx;
    __syncthreads();
    if (g == 0) {
#pragma unroll
        for (int t = 1; t < 16; ++t) {
            s += ssum[t][c];
            mx = fmaxf(mx, smax[t][c]);
        }
        meanv[c] = s * (1.0f / N);
        maxv[c] = mx;
    }
}

// ------------------------------------------- final GEMM + LayerNorm + ReLU
__global__ void k_final(const float* __restrict__ ws, const float* __restrict__ Wd,
                        const float* __restrict__ bd, const float* __restrict__ lng,
                        const float* __restrict__ lnb, float* __restrict__ out) {
    __shared__ float xs[3 * DIM];
    int i = blockIdx.x;
    int c = threadIdx.x;              // block = 64 (one wave)
    xs[c] = ws[WS_ATT + i * DIM + c];
    xs[DIM + c] = ws[WS_MEAN + c];
    xs[2 * DIM + c] = ws[WS_MAX + c];
    __syncthreads();
    float h = bd[c];
#pragma unroll
    for (int kk = 0; kk < 3 * DIM; ++kk) h += xs[kk] * Wd[kk * DIM + c];
    // LayerNorm across the 64 lanes
    float s = h;
#pragma unroll
    for (int off = 32; off >= 1; off >>= 1) s += __shfl_xor(s, off);
    float mu = s * (1.0f / DIM);
    float dif = h - mu;
    float s2 = dif * dif;
#pragma unroll
    for (int off = 32; off >= 1; off >>= 1) s2 += __shfl_xor(s2, off);
    float var = s2 * (1.0f / DIM);
    float rs = rsqrtf(var + 1e-5f);
    float o = dif * rs * lng[c] + lnb[c];
    out[i * DIM + c] = fmaxf(o, 0.0f);
}

// ---------------------------------------------------------------- launcher
extern "C" void kernel_launch(void* const* d_in, const int* in_sizes, int n_in,
                              void* d_out, int out_size, void* d_ws, size_t ws_size,
                              hipStream_t stream) {
    (void)in_sizes; (void)n_in; (void)out_size; (void)ws_size;
    const float* feat = (const float*)d_in[0];
    const float* dist = (const float*)d_in[1];
    const float* Wqkv = (const float*)d_in[2];
    const float* bqkv = (const float*)d_in[3];
    const float* Wg1  = (const float*)d_in[4];
    const float* bg1  = (const float*)d_in[5];
    const float* Wg2  = (const float*)d_in[6];
    const float* bg2  = (const float*)d_in[7];
    const float* tx   = (const float*)d_in[8];
    const float* ty   = (const float*)d_in[9];
    const float* tz   = (const float*)d_in[10];
    const float* Wd   = (const float*)d_in[11];
    const float* bd   = (const float*)d_in[12];
    const float* lng  = (const float*)d_in[13];
    const float* lnb  = (const float*)d_in[14];
    float* ws = (float*)d_ws;
    int* idxp = (int*)d_ws + WS_IDX;
    float* out = (float*)d_out;

    hipLaunchKernelGGL(k_idx, dim3((N * N + 255) / 256), dim3(256), 0, stream, dist, idxp);
    hipLaunchKernelGGL(k_qkv, dim3(N), dim3(192), 0, stream, feat, Wqkv, bqkv, Wg1, bg1, ws);
    hipLaunchKernelGGL(k_attn, dim3(N), dim3(256), 0, stream, tx, ty, tz, Wg2, bg2, ws, idxp);
    hipLaunchKernelGGL(k_colred, dim3(1), dim3(1024), 0, stream, ws + WS_ATT, ws + WS_MEAN,
                       ws + WS_MAX);
    hipLaunchKernelGGL(k_final, dim3(N), dim3(64), 0, stream, ws, Wd, bd, lng, lnb, out);
}

// Round 5
// 141.472 us; speedup vs baseline: 1.4294x; 1.4294x over previous
//
#include <hip/hip_runtime.h>
#include <hip/hip_bf16.h>
#include <math.h>

#define N 512
#define DIM 64

typedef __attribute__((ext_vector_type(8))) short short8;
typedef __attribute__((ext_vector_type(4))) float f32x4;

// workspace layout (units: floats from base)
#define WS_Q 0
#define WS_K (N*DIM)
#define WS_V (2*N*DIM)
#define WS_A (3*N*DIM)
#define WS_B (4*N*DIM)
#define WS_ATT (5*N*DIM)
#define WS_MEAN (6*N*DIM)
#define WS_MAXK (6*N*DIM + DIM)   // uint keys

__device__ __forceinline__ unsigned short f2bf(float f) {
    unsigned u = __float_as_uint(f);
    return (unsigned short)((u + 0x7fffu + ((u >> 16) & 1u)) >> 16);
}

// ------------------------------------------------- qkv + A/B precompute
// A_i = q_i @ Wg1 + bg1 ; B_j = k_j @ Wg1   (so hidden = relu(A_i - B_j))
__global__ void k_qkv(const float* __restrict__ feat, const float* __restrict__ Wqkv,
                      const float* __restrict__ bqkv, const float* __restrict__ Wg1,
                      const float* __restrict__ bg1, float* __restrict__ ws) {
    __shared__ float frow[DIM];
    __shared__ float qrow[DIM];
    __shared__ float krow[DIM];
    int i = blockIdx.x;
    int c = threadIdx.x;              // 0..191
    if (i == 0 && c < DIM) {          // init global reduction buffers
        ws[WS_MEAN + c] = 0.0f;
        ((unsigned*)ws)[WS_MAXK + c] = 0u;
    }
    if (c < DIM) frow[c] = feat[i * DIM + c];
    __syncthreads();
    float acc = bqkv[c];
#pragma unroll
    for (int kk = 0; kk < DIM; ++kk) acc += frow[kk] * Wqkv[kk * 3 * DIM + c];
    if (c < DIM) {
        ws[WS_Q + i * DIM + c] = acc;
        qrow[c] = acc;
    } else if (c < 2 * DIM) {
        ws[WS_K + i * DIM + (c - DIM)] = acc;
        krow[c - DIM] = acc;
    } else {
        ws[WS_V + i * DIM + (c - 2 * DIM)] = acc;
    }
    __syncthreads();
    if (c < DIM) {
        float a = bg1[c];
#pragma unroll
        for (int kk = 0; kk < DIM; ++kk) a += qrow[kk] * Wg1[kk * DIM + c];
        ws[WS_A + i * DIM + c] = a;
    } else if (c < 2 * DIM) {
        int cc = c - DIM;
        float b = 0.0f;
#pragma unroll
        for (int kk = 0; kk < DIM; ++kk) b += krow[kk] * Wg1[kk * DIM + cc];
        ws[WS_B + i * DIM + cc] = b;
    }
}

// ---------------------------------------------------------- fused attention
// one block per query row i; 4 waves; per 64-j chunk each wave MFMAs its
// 16-row H tile against Wg2 held in registers; barrier-free main loop.
__global__ __launch_bounds__(256, 2) void k_attn(
    const float* __restrict__ dist,
    const float* __restrict__ tx, const float* __restrict__ ty,
    const float* __restrict__ tz, const float* __restrict__ Wg2,
    const float* __restrict__ bg2, float* __restrict__ ws) {
    __shared__ float stx[3 * 24 * 65];
    __shared__ float sty[3 * 24 * 65];
    __shared__ float stz[3 * 16 * 65];
    __shared__ int sidx[N];
    __shared__ float smrg[4][4][16][3];

    const int i = blockIdx.x;
    const int tid = threadIdx.x;
    const int w = tid >> 6;
    const int lane = tid & 63;
    const int l15 = lane & 15;
    const int kg = lane >> 4;

    // stage tables (pad stride 64->65 to spread banks across gather groups)
    for (int t = tid; t < 3 * 24 * 64; t += 256) {
        int row = t >> 6, col = t & 63;
        stx[row * 65 + col] = tx[t];
        sty[row * 65 + col] = ty[t];
    }
    for (int t = tid; t < 3 * 16 * 64; t += 256) {
        int row = t >> 6, col = t & 63;
        stz[row * 65 + col] = tz[t];
    }
    // fused idx quantization for this i-row
    for (int j = tid; j < N; j += 256) {
        const float* dp = dist + ((size_t)i * N + j) * 3;
        int ix = min((int)floorf((dp[0] + 3.0f) * 4.0f), 23);
        int iy = min((int)floorf((dp[1] + 3.0f) * 4.0f), 23);
        int iz = min((int)floorf((dp[2] + 2.0f) * 4.0f), 15);
        sidx[j] = ix | (iy << 5) | (iz << 10);
    }

    // Wg2 held as MFMA B-fragments: lane holds Wg2[k][d], d=n*16+l15, k=kg*8+e+32*ks
    short8 wB[2][4];
#pragma unroll
    for (int ks = 0; ks < 2; ++ks)
#pragma unroll
        for (int n = 0; n < 4; ++n) {
            union { short8 v; unsigned short u[8]; } tmp;
#pragma unroll
            for (int e = 0; e < 8; ++e)
                tmp.u[e] = f2bf(Wg2[(ks * 32 + kg * 8 + e) * DIM + n * 16 + l15]);
            wB[ks][n] = tmp.v;
        }

    // A_i slices for this lane's k-positions (f32, converted per chunk)
    float af[16];
    {
        const float* ap = ws + WS_A + i * DIM + kg * 8;
#pragma unroll
        for (int e = 0; e < 8; ++e) { af[e] = ap[e]; af[8 + e] = ap[32 + e]; }
    }
    float qr[4], br[4];
#pragma unroll
    for (int n = 0; n < 4; ++n) {
        qr[n] = ws[WS_Q + i * DIM + n * 16 + l15];
        br[n] = bg2[n * 16 + l15];
    }

    const float* Bp = ws + WS_B;
    const float* Kp = ws + WS_K;
    const float* Vp = ws + WS_V;

    float stm[4], stl[4], sta[4];
#pragma unroll
    for (int n = 0; n < 4; ++n) { stm[n] = -INFINITY; stl[n] = 0.f; sta[n] = 0.f; }

    __syncthreads();

    const float LOG2E = 1.4426950408889634f;

    for (int cb = 0; cb < N; cb += 64) {
        // H A-fragment: row j = cb + w*16 + l15, k = dp
        int jA = cb + w * 16 + l15;
        const float* bb = Bp + jA * DIM + kg * 8;
        union { short8 v; unsigned short u[8]; } h0, h1;
#pragma unroll
        for (int e = 0; e < 8; ++e) {
            h0.u[e] = f2bf(fmaxf(af[e] - bb[e], 0.f));
            h1.u[e] = f2bf(fmaxf(af[8 + e] - bb[32 + e], 0.f));
        }
        f32x4 acc[4];
#pragma unroll
        for (int n = 0; n < 4; ++n) {
            acc[n] = (f32x4)(0.f);
            acc[n] = __builtin_amdgcn_mfma_f32_16x16x32_bf16(h0.v, wB[0][n], acc[n], 0, 0, 0);
            acc[n] = __builtin_amdgcn_mfma_f32_16x16x32_bf16(h1.v, wB[1][n], acc[n], 0, 0, 0);
        }
        // epilogue: C layout col=l15 (d), row=kg*4+r (j within tile)
        int j0 = cb + w * 16 + kg * 4;
        int pk[4];
#pragma unroll
        for (int r = 0; r < 4; ++r) pk[r] = sidx[j0 + r];
#pragma unroll
        for (int n = 0; n < 4; ++n) {
            int dof = n * 16 + l15;
            float rel2[4], vvv[4];
#pragma unroll
            for (int r = 0; r < 4; ++r) {
                int ix = pk[r] & 31, iy = (pk[r] >> 5) & 31, iz = pk[r] >> 10;
                float eq = stx[ix * 65 + dof] + sty[iy * 65 + dof] + stz[iz * 65 + dof];
                float ek = stx[(24 + ix) * 65 + dof] + sty[(24 + iy) * 65 + dof] +
                           stz[(16 + iz) * 65 + dof];
                float ev = stx[(48 + ix) * 65 + dof] + sty[(48 + iy) * 65 + dof] +
                           stz[(32 + iz) * 65 + dof];
                int j = j0 + r;
                float kv = Kp[j * DIM + dof];
                float vv = Vp[j * DIM + dof];
                float rel = acc[n][r] + br[n] + qr[n] * eq + kv * ek;
                rel2[r] = rel * LOG2E;
                vvv[r] = vv + ev;
            }
            float mx = fmaxf(fmaxf(rel2[0], rel2[1]), fmaxf(rel2[2], rel2[3]));
            float mn = fmaxf(stm[n], mx);
            float sc = exp2f(stm[n] - mn);
            float sl = 0.f, sa = 0.f;
#pragma unroll
            for (int r = 0; r < 4; ++r) {
                float p = exp2f(rel2[r] - mn);
                sl += p;
                sa += p * vvv[r];
            }
            stl[n] = stl[n] * sc + sl;
            sta[n] = sta[n] * sc + sa;
            stm[n] = mn;
        }
    }

    // reduce over j-groups within wave (lanes kg=0..3 hold same d)
#pragma unroll
    for (int n = 0; n < 4; ++n) {
#pragma unroll
        for (int off = 16; off <= 32; off <<= 1) {
            float om = __shfl_xor(stm[n], off);
            float ol = __shfl_xor(stl[n], off);
            float oa = __shfl_xor(sta[n], off);
            float mn = fmaxf(stm[n], om);
            float s1 = exp2f(stm[n] - mn), s2 = exp2f(om - mn);
            stl[n] = stl[n] * s1 + ol * s2;
            sta[n] = sta[n] * s1 + oa * s2;
            stm[n] = mn;
        }
        if (lane < 16) {
            smrg[w][n][l15][0] = stm[n];
            smrg[w][n][l15][1] = stl[n];
            smrg[w][n][l15][2] = sta[n];
        }
    }
    __syncthreads();
    if (tid < DIM) {
        int n = tid >> 4, c = tid & 15;
        float m = smrg[0][n][c][0], l = smrg[0][n][c][1], a = smrg[0][n][c][2];
#pragma unroll
        for (int ww = 1; ww < 4; ++ww) {
            float om = smrg[ww][n][c][0], ol = smrg[ww][n][c][1], oa = smrg[ww][n][c][2];
            float mn = fmaxf(m, om);
            float s1 = exp2f(m - mn), s2 = exp2f(om - mn);
            l = l * s1 + ol * s2;
            a = a * s1 + oa * s2;
            m = mn;
        }
        float att = a / l;
        ws[WS_ATT + i * DIM + tid] = att;
        atomicAdd(ws + WS_MEAN + tid, att);
        unsigned u = __float_as_uint(att);
        unsigned key = (u & 0x80000000u) ? ~u : (u | 0x80000000u);
        atomicMax((unsigned*)ws + WS_MAXK + tid, key);
    }
}

// ------------------------------------------- final GEMM + LayerNorm + ReLU
__global__ void k_final(const float* __restrict__ ws, const float* __restrict__ Wd,
                        const float* __restrict__ bd, const float* __restrict__ lng,
                        const float* __restrict__ lnb, float* __restrict__ out) {
    __shared__ float xs[3 * DIM];
    int i = blockIdx.x;
    int c = threadIdx.x;              // block = 64 (one wave)
    xs[c] = ws[WS_ATT + i * DIM + c];
    xs[DIM + c] = ws[WS_MEAN + c] * (1.0f / (float)N);
    unsigned key = ((const unsigned*)ws)[WS_MAXK + c];
    unsigned ub = (key & 0x80000000u) ? (key & 0x7fffffffu) : ~key;
    xs[2 * DIM + c] = __uint_as_float(ub);
    __syncthreads();
    float h = bd[c];
#pragma unroll
    for (int kk = 0; kk < 3 * DIM; ++kk) h += xs[kk] * Wd[kk * DIM + c];
    float s = h;
#pragma unroll
    for (int off = 32; off >= 1; off >>= 1) s += __shfl_xor(s, off);
    float mu = s * (1.0f / DIM);
    float dif = h - mu;
    float s2 = dif * dif;
#pragma unroll
    for (int off = 32; off >= 1; off >>= 1) s2 += __shfl_xor(s2, off);
    float var = s2 * (1.0f / DIM);
    float rs = rsqrtf(var + 1e-5f);
    float o = dif * rs * lng[c] + lnb[c];
    out[i * DIM + c] = fmaxf(o, 0.0f);
}

// ---------------------------------------------------------------- launcher
extern "C" void kernel_launch(void* const* d_in, const int* in_sizes, int n_in,
                              void* d_out, int out_size, void* d_ws, size_t ws_size,
                              hipStream_t stream) {
    (void)in_sizes; (void)n_in; (void)out_size; (void)ws_size;
    const float* feat = (const float*)d_in[0];
    const float* dist = (const float*)d_in[1];
    const float* Wqkv = (const float*)d_in[2];
    const float* bqkv = (const float*)d_in[3];
    const float* Wg1  = (const float*)d_in[4];
    const float* bg1  = (const float*)d_in[5];
    const float* Wg2  = (const float*)d_in[6];
    const float* bg2  = (const float*)d_in[7];
    const float* tx   = (const float*)d_in[8];
    const float* ty   = (const float*)d_in[9];
    const float* tz   = (const float*)d_in[10];
    const float* Wd   = (const float*)d_in[11];
    const float* bd   = (const float*)d_in[12];
    const float* lng  = (const float*)d_in[13];
    const float* lnb  = (const float*)d_in[14];
    float* ws = (float*)d_ws;
    float* out = (float*)d_out;

    hipLaunchKernelGGL(k_qkv, dim3(N), dim3(192), 0, stream, feat, Wqkv, bqkv, Wg1, bg1, ws);
    hipLaunchKernelGGL(k_attn, dim3(N), dim3(256), 0, stream, dist, tx, ty, tz, Wg2, bg2, ws);
    hipLaunchKernelGGL(k_final, dim3(N), dim3(64), 0, stream, ws, Wd, bd, lng, lnb, out);
}